// Round 14
// baseline (3700.628 us; speedup 1.0000x reference)
//
#include <hip/hip_runtime.h>
#include <hip/hip_bf16.h>
#include <cstddef>

// Problem constants (fixed by the reference)
#define TT    256
#define NROW  2048
#define GBN   5
#define EDG   65536

using f32x4  = __attribute__((ext_vector_type(4))) float;
using bf16x8 = __attribute__((ext_vector_type(8))) short;

__device__ __forceinline__ void pinv(bf16x8& x) { asm volatile("" : "+v"(x)); }

__device__ __forceinline__ void barrier_lgkm() {
  asm volatile("s_waitcnt lgkmcnt(0)" ::: "memory");
  __builtin_amdgcn_s_barrier();
}

// fast transcendentals
__device__ __forceinline__ float exp2fa(float x) { float r; asm("v_exp_f32 %0, %1" : "=v"(r) : "v"(x)); return r; }
__device__ __forceinline__ float rcpfa(float x)  { float r; asm("v_rcp_f32 %0, %1" : "=v"(r) : "v"(x)); return r; }
#define L2E 1.4426950408889634f
__device__ __forceinline__ float sigf(float x) { return rcpfa(1.0f + exp2fa(x * -L2E)); }
__device__ __forceinline__ float tanh_fast(float x) {
  float t = exp2fa(x * (-2.0f * L2E));
  return (1.0f - t) * rcpfa(1.0f + t);
}

// ---------------- workspace float offsets ----------------
enum : int {
  XBUF   = 425984,   // [2048][128] f32
  GBUFO  = 688128,   // [5][128]
  DINVP  = 688768,
  DINVT  = 690816,
  H16    = 692864,
  PG1    = 725632,
  H128   = 758400,
  PGB    = 1020544,
  TG1    = 1282688,
  TGB    = 1315456,
  WS_END = 1577600
};

enum : int {
  N_P0   = 0,
  N_P1I  = 65536,
  N_P1H  = 131072,
  N_PA   = 196608,
  N_T0   = 212992,
  N_T1I  = 278528,
  N_T1H  = 344064,
  N_TA   = 409600
};

// chunked-path state (16-row b16 indexing, as round 12)
enum : long long {
  C0S_O   = 1577600,   // 129*2048
  C1S_O   = 1841792,   // 129*2048
  H1IMG_O = 2105984,   // 129*4096 ushort = 264192 f
  SMST_O  = 2370176,   // 129*32
  NUMS_O  = 2374304,   // 264192
  ACCOS_O = 2638496,   // 264192
  H0S_O   = 2902688    // [129][TC][4096] ushort h0 frag stream; pre1 follows
};

// shared overlay; padded so only ONE block fits per CU (round-12/13 lesson)
struct __align__(16) SmemPipe {
  ushort a[2][4096];    // L0: h0 hi dbuf (first 2048); L1: h1 hi dbuf [tile*2048]
  ushort b[2][4096];    // lo counterpart
  float  x[2560];       // L0 xsa: [32 steps][16 rows][5]
  float  s[2][8][32];   // L1 sbuf [dbuf][wave][tile*16+row]
  float  pad[10240];    // occupancy limiter (~84KB total)
};

// ---------------- weight fragment packing ----------------
__global__ void k_pack(const float* __restrict__ Wa, const float* __restrict__ Wb,
                       int K1, int K2, int NT, int KS, ushort* __restrict__ dst) {
  int t = blockIdx.x * blockDim.x + threadIdx.x;
  int total = KS * NT * 2 * 64;
  if (t >= total) return;
  int lane = t & 63;
  int part = (t >> 6) & 1;
  int rest = t >> 7;
  int nt = rest % NT, kk = rest / NT;
  int j = nt * 16 + (lane & 15);
  int kbase = kk * 32 + (lane >> 4) * 8;
  bf16x8 o;
  #pragma unroll
  for (int e = 0; e < 8; ++e) {
    int k = kbase + e;
    float x = (k < K1) ? Wa[(size_t)j * K1 + k] : Wb[(size_t)j * K2 + (k - K1)];
    __hip_bfloat16 hi = __float2bfloat16(x);
    ushort u;
    if (part == 0) {
      u = *(ushort*)&hi;
    } else {
      float lo = x - __bfloat162float(hi);
      __hip_bfloat16 lob = __float2bfloat16(lo);
      u = *(ushort*)&lob;
    }
    o[e] = (short)u;
  }
  ((bf16x8*)dst)[t] = o;
}

// ---------------- misc prep ----------------
__global__ void k_zero(float* __restrict__ p, int n) {
  int i = blockIdx.x * blockDim.x + threadIdx.x;
  if (i < n) p[i] = 0.0f;
}
__global__ void k_fill1(float* __restrict__ p, int n) {
  int i = blockIdx.x * blockDim.x + threadIdx.x;
  if (i < n) p[i] = 1.0f;
}
__global__ void k_deg(const int* __restrict__ col, const float* __restrict__ w,
                      float* __restrict__ deg, int n) {
  int i = blockIdx.x * blockDim.x + threadIdx.x;
  if (i < n) atomicAdd(&deg[col[i]], w[i]);
}
__global__ void k_dinv(float* __restrict__ deg, int n) {
  int i = blockIdx.x * blockDim.x + threadIdx.x;
  if (i < n) deg[i] = rsqrtf(deg[i]);
}

// =====================================================================
// Role A: layer-0 recurrence, 16 rows/block (129 blocks), Whh0 pinned,
// x-chunk in LDS, dbuf image, 1 lgkm barrier/step. (round-12 version)
// =====================================================================
__device__ static void lstm0_body(
    SmemPipe* sm, int b,
    const float* __restrict__ price, const float* __restrict__ gtrend,
    const float* __restrict__ ws_ro, ushort* __restrict__ h0S, float* __restrict__ c0S,
    const float* __restrict__ Wih0p, const float* __restrict__ bi0p, const float* __restrict__ bh0p,
    const float* __restrict__ Wih0t, const float* __restrict__ bi0t, const float* __restrict__ bh0t,
    int nPrice, int t0, int TCp, int first)
{
  const int tid = threadIdx.x;
  const int w = tid >> 6, l = tid & 63;
  const int lq = l >> 4, lr = l & 15;
  const int rb = lq * 4;
  const int kcol = w * 16 + lr;
  const bool isP = b < nPrice;
  const int R = isP ? 16 : GBN;
  const float* seq = isP ? (price + (size_t)b * 16 * (TT * 5)) : gtrend;
  const ushort* S0 = (const ushort*)(ws_ro + (isP ? N_P0 : N_T0));
  const float* Wih0 = isP ? Wih0p : Wih0t;
  const float* bi0 = isP ? bi0p : bi0t;
  const float* bh0 = isP ? bh0p : bh0t;

  auto h0hi = sm->a;
  auto h0lo = sm->b;
  float* xsa = sm->x;

  bf16x8 wh[4][4], wl[4][4];
  #pragma unroll
  for (int kk = 0; kk < 4; ++kk)
    #pragma unroll
    for (int g = 0; g < 4; ++g) {
      int blk = (kk * 32 + (w + 8 * g)) * 2;
      wh[kk][g] = ((const bf16x8*)S0)[(blk + 0) * 64 + l];
      wl[kk][g] = ((const bf16x8*)S0)[(blk + 1) * 64 + l];
      pinv(wh[kk][g]); pinv(wl[kk][g]);
    }
  float wih0r[4][5], bg0[4];
  #pragma unroll
  for (int g = 0; g < 4; ++g) {
    int j = kcol + 128 * g;
    bg0[g] = bi0[j] + bh0[j];
    #pragma unroll
    for (int k = 0; k < 5; ++k) wih0r[g][k] = Wih0[j * 5 + k];
  }

  const size_t bstr = (size_t)b * (size_t)TCp * 4096;
  float c0[4] = {0, 0, 0, 0};

  for (int i = tid; i < TCp * 80; i += 512) {
    int tl = i / 80, rem = i % 80, r = rem / 5, k = rem % 5;
    xsa[tl * 80 + rem] = (r < R) ? seq[(size_t)r * (TT * 5) + (size_t)(t0 + tl) * 5 + k] : 0.0f;
  }
  if (first) {
    for (int i = tid; i < 2048; i += 512) { h0hi[0][i] = 0; h0lo[0][i] = 0; }
  } else {
    const size_t lb = bstr + (size_t)(TCp - 1) * 4096;
    *(uint2*)&h0hi[0][4 * tid] = *(const uint2*)&h0S[lb + 4 * tid];
    *(uint2*)&h0lo[0][4 * tid] = *(const uint2*)&h0S[lb + 2048 + 4 * tid];
    #pragma unroll
    for (int reg = 0; reg < 4; ++reg)
      c0[reg] = c0S[(size_t)b * 2048 + (size_t)(rb + reg) * 128 + kcol];
  }
  __syncthreads();

  const int kkhi = (kcol >> 3) & 3;
  const int eo = kcol & 7;
  const int b0w = rb + 16 * kkhi;
  const int kkw = kcol >> 5;
  int wro[4];
  #pragma unroll
  for (int reg = 0; reg < 4; ++reg) wro[reg] = kkw * 512 + (b0w + (reg ^ lq)) * 8 + eo;
  const int rdo = (l ^ ((l >> 2) & 3)) * 8;

  int cur = 0;
  for (int tl = 0; tl < TCp; ++tl) {
    const int nxt = cur ^ 1;
    if (tl > 0) {
      *(uint2*)&h0S[bstr + (size_t)(tl - 1) * 4096 + 4 * tid] = *(const uint2*)&h0hi[cur][4 * tid];
      *(uint2*)&h0S[bstr + (size_t)(tl - 1) * 4096 + 2048 + 4 * tid] = *(const uint2*)&h0lo[cur][4 * tid];
    }

    f32x4 acc[4];
    #pragma unroll
    for (int g = 0; g < 4; ++g) acc[g] = (f32x4){bg0[g], bg0[g], bg0[g], bg0[g]};
    #pragma unroll
    for (int k = 0; k < 5; ++k) {
      float xv[4];
      #pragma unroll
      for (int reg = 0; reg < 4; ++reg) xv[reg] = xsa[tl * 80 + (rb + reg) * 5 + k];
      #pragma unroll
      for (int g = 0; g < 4; ++g)
        #pragma unroll
        for (int reg = 0; reg < 4; ++reg)
          acc[g][reg] = fmaf(xv[reg], wih0r[g][k], acc[g][reg]);
    }
    #pragma unroll
    for (int kk = 0; kk < 4; ++kk) {
      bf16x8 ah = *(const bf16x8*)&h0hi[cur][kk * 512 + rdo];
      bf16x8 al = *(const bf16x8*)&h0lo[cur][kk * 512 + rdo];
      #pragma unroll
      for (int g = 0; g < 4; ++g) {
        acc[g] = __builtin_amdgcn_mfma_f32_16x16x32_bf16(ah, wh[kk][g], acc[g], 0, 0, 0);
        acc[g] = __builtin_amdgcn_mfma_f32_16x16x32_bf16(al, wh[kk][g], acc[g], 0, 0, 0);
        acc[g] = __builtin_amdgcn_mfma_f32_16x16x32_bf16(ah, wl[kk][g], acc[g], 0, 0, 0);
      }
    }
    #pragma unroll
    for (int reg = 0; reg < 4; ++reg) {
      float gi = acc[0][reg], gf = acc[1][reg], gg = acc[2][reg], go = acc[3][reg];
      float c = sigf(gf) * c0[reg] + sigf(gi) * tanh_fast(gg);
      c0[reg] = c;
      float h = sigf(go) * tanh_fast(c);
      __hip_bfloat16 hb = __float2bfloat16(h);
      float lo = h - __bfloat162float(hb);
      __hip_bfloat16 lb = __float2bfloat16(lo);
      h0hi[nxt][wro[reg]] = *(ushort*)&hb;
      h0lo[nxt][wro[reg]] = *(ushort*)&lb;
    }
    barrier_lgkm();
    cur = nxt;
  }
  *(uint2*)&h0S[bstr + (size_t)(TCp - 1) * 4096 + 4 * tid] = *(const uint2*)&h0hi[cur][4 * tid];
  *(uint2*)&h0S[bstr + (size_t)(TCp - 1) * 4096 + 2048 + 4 * tid] = *(const uint2*)&h0lo[cur][4 * tid];

  #pragma unroll
  for (int reg = 0; reg < 4; ++reg)
    c0S[(size_t)b * 2048 + (size_t)(rb + reg) * 128 + kcol] = c0[reg];
}

// =====================================================================
// Role B: layer-1 recurrence, 32 rows/block = 2 tiles (round-14 rebalance:
// L1 was the shorter role; 65 blocks). Tile t maps to 16-row block index
// b16 = 2*b32+t (trend: b32=64, tile0=b16 128, tile1 inert).
// =====================================================================
__device__ static void lstm1_body(
    SmemPipe* sm, int b32,
    const float* __restrict__ pre1, const float* __restrict__ ws_ro,
    float* __restrict__ xout, float* __restrict__ gout,
    float* __restrict__ c1S, ushort* __restrict__ h1imgS, float* __restrict__ smS,
    float* __restrict__ numS, float* __restrict__ accOS,
    const float* __restrict__ apB1, const float* __restrict__ apW2, const float* __restrict__ apB2,
    const float* __restrict__ atB1, const float* __restrict__ atW2, const float* __restrict__ atB2,
    int TCp, int first)
{
  const int tid = threadIdx.x;
  const int w = tid >> 6, l = tid & 63;
  const int lq = l >> 4, lr = l & 15;
  const int rb = lq * 4;
  const int kcol = w * 16 + lr;
  const bool isP = b32 < 64;
  const bool t1on = isP;
  const int bb0 = isP ? 2 * b32 : 128;
  const int bb1 = isP ? 2 * b32 + 1 : 128;
  const ushort* S1H = (const ushort*)(ws_ro + (isP ? N_P1H : N_T1H));
  const ushort* SA  = (const ushort*)(ws_ro + (isP ? N_PA : N_TA));
  const float* b1ap = isP ? apB1 : atB1;
  const float* w2p  = isP ? apW2 : atW2;
  const float  b2v  = isP ? apB2[0] : atB2[0];

  auto h1hi = sm->a;   // [2 dbuf][tile*2048 + idx]
  auto h1lo = sm->b;
  auto sbuf = sm->s;   // [2][8][32]

  bf16x8 hh[4][4], hl[4][4];
  #pragma unroll
  for (int kk = 0; kk < 4; ++kk)
    #pragma unroll
    for (int g = 0; g < 4; ++g) {
      int blk = (kk * 32 + (w + 8 * g)) * 2;
      hh[kk][g] = ((const bf16x8*)S1H)[(blk + 0) * 64 + l];
      hl[kk][g] = ((const bf16x8*)S1H)[(blk + 1) * 64 + l];
      pinv(hh[kk][g]); pinv(hl[kk][g]);
    }
  bf16x8 wa[4], wal[4];
  #pragma unroll
  for (int kk = 0; kk < 4; ++kk) {
    wa[kk]  = ((const bf16x8*)SA)[((kk * 8 + w) * 2 + 0) * 64 + l];
    wal[kk] = ((const bf16x8*)SA)[((kk * 8 + w) * 2 + 1) * 64 + l];
    pinv(wa[kk]); pinv(wal[kk]);
  }
  const float w2r = w2p[kcol], b1ar = b1ap[kcol];

  float c1[2][4] = {{0,0,0,0},{0,0,0,0}}, h1r[2][4] = {{0,0,0,0},{0,0,0,0}}, h1rp[2][4];
  float num[2][4] = {{0,0,0,0},{0,0,0,0}}, accO[2][4] = {{0,0,0,0},{0,0,0,0}};
  float m_run[2][4], den_r[2][4];
  #pragma unroll
  for (int t = 0; t < 2; ++t)
    #pragma unroll
    for (int reg = 0; reg < 4; ++reg) { m_run[t][reg] = -1e30f; den_r[t][reg] = 0.0f; }

  if (first) {
    for (int i = tid; i < 4096; i += 512) { h1hi[0][i] = 0; h1lo[0][i] = 0; }
  } else {
    // tile 0 restore
    {
      const size_t ib = (size_t)bb0 * 4096;
      *(uint2*)&h1hi[0][4 * tid] = *(const uint2*)&h1imgS[ib + 4 * tid];
      *(uint2*)&h1lo[0][4 * tid] = *(const uint2*)&h1imgS[ib + 2048 + 4 * tid];
      const size_t sb = (size_t)bb0 * 2048;
      #pragma unroll
      for (int reg = 0; reg < 4; ++reg) {
        size_t o = sb + (size_t)(rb + reg) * 128 + kcol;
        c1[0][reg] = c1S[o];
        num[0][reg] = numS[o];
        accO[0][reg] = accOS[o];
        m_run[0][reg] = smS[(size_t)bb0 * 32 + (size_t)(rb + reg) * 2];
        den_r[0][reg] = smS[(size_t)bb0 * 32 + (size_t)(rb + reg) * 2 + 1];
      }
    }
    if (t1on) {
      const size_t ib = (size_t)bb1 * 4096;
      *(uint2*)&h1hi[0][2048 + 4 * tid] = *(const uint2*)&h1imgS[ib + 4 * tid];
      *(uint2*)&h1lo[0][2048 + 4 * tid] = *(const uint2*)&h1imgS[ib + 2048 + 4 * tid];
      const size_t sb = (size_t)bb1 * 2048;
      #pragma unroll
      for (int reg = 0; reg < 4; ++reg) {
        size_t o = sb + (size_t)(rb + reg) * 128 + kcol;
        c1[1][reg] = c1S[o];
        num[1][reg] = numS[o];
        accO[1][reg] = accOS[o];
        m_run[1][reg] = smS[(size_t)bb1 * 32 + (size_t)(rb + reg) * 2];
        den_r[1][reg] = smS[(size_t)bb1 * 32 + (size_t)(rb + reg) * 2 + 1];
      }
    }
  }
  __syncthreads();

  const int kkhi = (kcol >> 3) & 3;
  const int eo = kcol & 7;
  const int b0w = rb + 16 * kkhi;
  const int kkw = kcol >> 5;
  int wro[4];
  #pragma unroll
  for (int reg = 0; reg < 4; ++reg) wro[reg] = kkw * 512 + (b0w + (reg ^ lq)) * 8 + eo;
  const int rdo = (l ^ ((l >> 2) & 3)) * 8;

  const float* pbA = pre1 + (size_t)bb0 * TCp * 8192 + (size_t)tid * 16;
  const float* pbB = pre1 + (size_t)bb1 * TCp * 8192 + (size_t)tid * 16;

  f32x4 pnA[4], pnB[4];
  #pragma unroll
  for (int g = 0; g < 4; ++g) { pnA[g] = *(const f32x4*)&pbA[g * 4]; pnB[g] = *(const f32x4*)&pbB[g * 4]; }

  int cur = 0;
  for (int tl = 0; tl < TCp; ++tl) {
    const int nxt = cur ^ 1;
    f32x4 acc[2][4];
    #pragma unroll
    for (int g = 0; g < 4; ++g) { acc[0][g] = pnA[g]; acc[1][g] = pnB[g]; }
    if (tl + 1 < TCp) {
      #pragma unroll
      for (int g = 0; g < 4; ++g) {
        pnA[g] = *(const f32x4*)&pbA[(size_t)(tl + 1) * 8192 + g * 4];
        pnB[g] = *(const f32x4*)&pbB[(size_t)(tl + 1) * 8192 + g * 4];
      }
    }

    #pragma unroll
    for (int kk = 0; kk < 4; ++kk) {
      bf16x8 ah0 = *(const bf16x8*)&h1hi[cur][kk * 512 + rdo];
      bf16x8 al0 = *(const bf16x8*)&h1lo[cur][kk * 512 + rdo];
      bf16x8 ah1 = *(const bf16x8*)&h1hi[cur][2048 + kk * 512 + rdo];
      bf16x8 al1 = *(const bf16x8*)&h1lo[cur][2048 + kk * 512 + rdo];
      #pragma unroll
      for (int g = 0; g < 4; ++g) {
        acc[0][g] = __builtin_amdgcn_mfma_f32_16x16x32_bf16(ah0, hh[kk][g], acc[0][g], 0, 0, 0);
        acc[0][g] = __builtin_amdgcn_mfma_f32_16x16x32_bf16(al0, hh[kk][g], acc[0][g], 0, 0, 0);
        acc[0][g] = __builtin_amdgcn_mfma_f32_16x16x32_bf16(ah0, hl[kk][g], acc[0][g], 0, 0, 0);
        acc[1][g] = __builtin_amdgcn_mfma_f32_16x16x32_bf16(ah1, hh[kk][g], acc[1][g], 0, 0, 0);
        acc[1][g] = __builtin_amdgcn_mfma_f32_16x16x32_bf16(al1, hh[kk][g], acc[1][g], 0, 0, 0);
        acc[1][g] = __builtin_amdgcn_mfma_f32_16x16x32_bf16(ah1, hl[kk][g], acc[1][g], 0, 0, 0);
      }
    }
    #pragma unroll
    for (int t = 0; t < 2; ++t)
      #pragma unroll
      for (int reg = 0; reg < 4; ++reg) {
        h1rp[t][reg] = h1r[t][reg];
        float gi = acc[t][0][reg], gf = acc[t][1][reg], gg = acc[t][2][reg], go = acc[t][3][reg];
        float c = sigf(gf) * c1[t][reg] + sigf(gi) * tanh_fast(gg);
        c1[t][reg] = c;
        float h = sigf(go) * tanh_fast(c);
        h1r[t][reg] = h;
        __hip_bfloat16 hb = __float2bfloat16(h);
        float lo = h - __bfloat162float(hb);
        __hip_bfloat16 lb = __float2bfloat16(lo);
        h1hi[nxt][t * 2048 + wro[reg]] = *(ushort*)&hb;
        h1lo[nxt][t * 2048 + wro[reg]] = *(ushort*)&lb;
      }
    barrier_lgkm();

    if (tl > 0) {
      const int pb = (tl - 1) & 1;
      #pragma unroll
      for (int t = 0; t < 2; ++t)
        #pragma unroll
        for (int reg = 0; reg < 4; ++reg) {
          float s = b2v;
          #pragma unroll
          for (int ww = 0; ww < 8; ++ww) s += sbuf[pb][ww][t * 16 + rb + reg];
          float m0 = m_run[t][reg];
          float nm = fmaxf(m0, s);
          float e = exp2fa((s - nm) * L2E), sc = exp2fa((m0 - nm) * L2E);
          float d = den_r[t][reg] * sc + e;
          m_run[t][reg] = nm; den_r[t][reg] = d;
          num[t][reg] = num[t][reg] * sc + e * h1rp[t][reg];
          accO[t][reg] = fmaf(num[t][reg], rcpfa(d), accO[t][reg]);
        }
    }

    f32x4 aa[2];
    aa[0] = (f32x4){b1ar, b1ar, b1ar, b1ar};
    aa[1] = aa[0];
    #pragma unroll
    for (int kk = 0; kk < 4; ++kk) {
      bf16x8 ah0 = *(const bf16x8*)&h1hi[nxt][kk * 512 + rdo];
      bf16x8 al0 = *(const bf16x8*)&h1lo[nxt][kk * 512 + rdo];
      bf16x8 ah1 = *(const bf16x8*)&h1hi[nxt][2048 + kk * 512 + rdo];
      bf16x8 al1 = *(const bf16x8*)&h1lo[nxt][2048 + kk * 512 + rdo];
      aa[0] = __builtin_amdgcn_mfma_f32_16x16x32_bf16(ah0, wa[kk], aa[0], 0, 0, 0);
      aa[0] = __builtin_amdgcn_mfma_f32_16x16x32_bf16(al0, wa[kk], aa[0], 0, 0, 0);
      aa[0] = __builtin_amdgcn_mfma_f32_16x16x32_bf16(ah0, wal[kk], aa[0], 0, 0, 0);
      aa[1] = __builtin_amdgcn_mfma_f32_16x16x32_bf16(ah1, wa[kk], aa[1], 0, 0, 0);
      aa[1] = __builtin_amdgcn_mfma_f32_16x16x32_bf16(al1, wa[kk], aa[1], 0, 0, 0);
      aa[1] = __builtin_amdgcn_mfma_f32_16x16x32_bf16(ah1, wal[kk], aa[1], 0, 0, 0);
    }
    float p[2][4];
    #pragma unroll
    for (int t = 0; t < 2; ++t)
      #pragma unroll
      for (int reg = 0; reg < 4; ++reg) p[t][reg] = tanh_fast(aa[t][reg]) * w2r;
    #pragma unroll
    for (int m = 1; m < 16; m <<= 1) {
      #pragma unroll
      for (int t = 0; t < 2; ++t)
        #pragma unroll
        for (int reg = 0; reg < 4; ++reg) p[t][reg] += __shfl_xor(p[t][reg], m);
    }
    if (lr == 0) {
      #pragma unroll
      for (int t = 0; t < 2; ++t)
        #pragma unroll
        for (int reg = 0; reg < 4; ++reg) sbuf[tl & 1][w][t * 16 + rb + reg] = p[t][reg];
    }
    cur = nxt;
  }
  barrier_lgkm();
  {
    const int pb = (TCp - 1) & 1;
    #pragma unroll
    for (int t = 0; t < 2; ++t)
      #pragma unroll
      for (int reg = 0; reg < 4; ++reg) {
        float s = b2v;
        #pragma unroll
        for (int ww = 0; ww < 8; ++ww) s += sbuf[pb][ww][t * 16 + rb + reg];
        float m0 = m_run[t][reg];
        float nm = fmaxf(m0, s);
        float e = exp2fa((s - nm) * L2E), sc = exp2fa((m0 - nm) * L2E);
        float d = den_r[t][reg] * sc + e;
        m_run[t][reg] = nm; den_r[t][reg] = d;
        num[t][reg] = num[t][reg] * sc + e * h1r[t][reg];
        accO[t][reg] = fmaf(num[t][reg], rcpfa(d), accO[t][reg]);
      }
  }

  // ---- store state + outputs per tile ----
  {
    const size_t ib0 = (size_t)bb0 * 4096;
    *(uint2*)&h1imgS[ib0 + 4 * tid] = *(const uint2*)&h1hi[cur][4 * tid];
    *(uint2*)&h1imgS[ib0 + 2048 + 4 * tid] = *(const uint2*)&h1lo[cur][4 * tid];
    if (t1on) {
      const size_t ib1 = (size_t)bb1 * 4096;
      *(uint2*)&h1imgS[ib1 + 4 * tid] = *(const uint2*)&h1hi[cur][2048 + 4 * tid];
      *(uint2*)&h1imgS[ib1 + 2048 + 4 * tid] = *(const uint2*)&h1lo[cur][2048 + 4 * tid];
    }
    #pragma unroll
    for (int t = 0; t < 2; ++t) {
      if (t == 1 && !t1on) continue;
      const int bbt = t == 0 ? bb0 : bb1;
      const size_t sb = (size_t)bbt * 2048;
      #pragma unroll
      for (int reg = 0; reg < 4; ++reg) {
        size_t o = sb + (size_t)(rb + reg) * 128 + kcol;
        c1S[o] = c1[t][reg];
        numS[o] = num[t][reg];
        accOS[o] = accO[t][reg];
      }
      if (w == 0 && lr == 0) {
        #pragma unroll
        for (int reg = 0; reg < 4; ++reg) {
          smS[(size_t)bbt * 32 + (size_t)(rb + reg) * 2] = m_run[t][reg];
          smS[(size_t)bbt * 32 + (size_t)(rb + reg) * 2 + 1] = den_r[t][reg];
        }
      }
      const int Rt = isP ? 16 : GBN;
      float* dstx = isP ? (xout + (size_t)bbt * 16 * 128) : gout;
      #pragma unroll
      for (int reg = 0; reg < 4; ++reg) {
        int r = rb + reg;
        if (r < Rt) dstx[(size_t)r * 128 + kcol] = accO[t][reg];
      }
    }
  }
}

// =====================================================================
// Fused pipeline: blocks 0..128 = L0(c) 16-row; 129..193 = L1(c-1) 32-row.
// 194 blocks, LDS-forced 1 block/CU.
// =====================================================================
__global__ __launch_bounds__(512, 2) void k_pipe(
    const float* __restrict__ price, const float* __restrict__ gtrend,
    const float* __restrict__ ws_ro, ushort* __restrict__ h0S, float* __restrict__ c0S,
    const float* __restrict__ Wih0p, const float* __restrict__ bi0p, const float* __restrict__ bh0p,
    const float* __restrict__ Wih0t, const float* __restrict__ bi0t, const float* __restrict__ bh0t,
    const float* __restrict__ pre1,
    float* __restrict__ xout, float* __restrict__ gout,
    float* __restrict__ c1S, ushort* __restrict__ h1imgS, float* __restrict__ smS,
    float* __restrict__ numS, float* __restrict__ accOS,
    const float* __restrict__ apB1, const float* __restrict__ apW2, const float* __restrict__ apB2,
    const float* __restrict__ atB1, const float* __restrict__ atW2, const float* __restrict__ atB2,
    int t0A, int TCp, int firstA, int firstB, int doA, int doB)
{
  __shared__ SmemPipe sm;
  const int bid = blockIdx.x;
  if (bid < 129) {
    if (doA)
      lstm0_body(&sm, bid, price, gtrend, ws_ro, h0S, c0S,
                 Wih0p, bi0p, bh0p, Wih0t, bi0t, bh0t, 128, t0A, TCp, firstA);
  } else {
    if (doB)
      lstm1_body(&sm, bid - 129, pre1, ws_ro, xout, gout,
                 c1S, h1imgS, smS, numS, accOS,
                 apB1, apW2, apB2, atB1, atW2, atB2, TCp, firstB);
  }
}

// =====================================================================
// k_pre1 — throughput GEMM: pre1[t] = h0[t] @ Wih1^T + b1 (round-12 form).
// =====================================================================
__global__ __launch_bounds__(512, 2) void k_pre1(
    const ushort* __restrict__ h0S, const float* __restrict__ ws_ro,
    float* __restrict__ pre1,
    const float* __restrict__ bi1p, const float* __restrict__ bh1p,
    const float* __restrict__ bi1t, const float* __restrict__ bh1t,
    int nPrice, int TCp, int nsub)
{
  const int b = blockIdx.x / nsub, sub = blockIdx.x % nsub;
  const int tid = threadIdx.x;
  const int w = tid >> 6, l = tid & 63;
  const int lr = l & 15;
  const int kcol = w * 16 + lr;
  const bool isP = b < nPrice;
  const ushort* S1I = (const ushort*)(ws_ro + (isP ? N_P1I : N_T1I));
  const float* bi1 = isP ? bi1p : bi1t;
  const float* bh1 = isP ? bh1p : bh1t;
  float bg1[4];
  #pragma unroll
  for (int g = 0; g < 4; ++g) bg1[g] = bi1[kcol + 128 * g] + bh1[kcol + 128 * g];
  const int rdo = (l ^ ((l >> 2) & 3)) * 8;
  const size_t bstr = (size_t)b * (size_t)TCp * 4096;
  const int t0 = sub * 4;

  f32x4 acc[4][4];
  #pragma unroll
  for (int ts = 0; ts < 4; ++ts)
    #pragma unroll
    for (int g = 0; g < 4; ++g) acc[ts][g] = (f32x4){bg1[g], bg1[g], bg1[g], bg1[g]};

  #pragma unroll
  for (int kk = 0; kk < 4; ++kk) {
    bf16x8 bh_[4], bl_[4];
    #pragma unroll
    for (int g = 0; g < 4; ++g) {
      int blk = (kk * 32 + (w + 8 * g)) * 2;
      bh_[g] = ((const bf16x8*)S1I)[(blk + 0) * 64 + l];
      bl_[g] = ((const bf16x8*)S1I)[(blk + 1) * 64 + l];
    }
    #pragma unroll
    for (int ts = 0; ts < 4; ++ts) {
      const size_t tb = bstr + (size_t)(t0 + ts) * 4096 + kk * 512 + rdo;
      bf16x8 ah = *(const bf16x8*)&h0S[tb];
      bf16x8 al = *(const bf16x8*)&h0S[tb + 2048];
      #pragma unroll
      for (int g = 0; g < 4; ++g) {
        acc[ts][g] = __builtin_amdgcn_mfma_f32_16x16x32_bf16(ah, bh_[g], acc[ts][g], 0, 0, 0);
        acc[ts][g] = __builtin_amdgcn_mfma_f32_16x16x32_bf16(al, bh_[g], acc[ts][g], 0, 0, 0);
        acc[ts][g] = __builtin_amdgcn_mfma_f32_16x16x32_bf16(ah, bl_[g], acc[ts][g], 0, 0, 0);
      }
    }
  }
  #pragma unroll
  for (int ts = 0; ts < 4; ++ts)
    #pragma unroll
    for (int g = 0; g < 4; ++g)
      *(f32x4*)&pre1[((size_t)b * TCp + (t0 + ts)) * 8192 + (size_t)tid * 16 + g * 4] = acc[ts][g];
}

// ---------------- GCN kernels ----------------
__global__ void k_lin(const float* __restrict__ x, const float* __restrict__ W,
                      float* __restrict__ h, int M, int K, int n) {
  int i = blockIdx.x * blockDim.x + threadIdx.x;
  if (i >= n) return;
  int r = i / M, m = i % M;
  const float* xr = x + (size_t)r * K;
  const float* wm = W + (size_t)m * K;
  float a = 0.f;
  for (int k = 0; k < K; ++k) a = fmaf(xr[k], wm[k], a);
  h[i] = a;
}

__global__ void k_scatter(const int* __restrict__ rowi, const int* __restrict__ coli,
                          const float* __restrict__ w, const float* __restrict__ dinv,
                          const float* __restrict__ h, float* __restrict__ outp,
                          int M, long long n) {
  long long i = (long long)blockIdx.x * blockDim.x + threadIdx.x;
  if (i >= n) return;
  int e = (int)(i / M), f = (int)(i % M);
  int rs = rowi[e], cd = coli[e];
  float nrm = dinv[rs] * w[e] * dinv[cd];
  atomicAdd(&outp[(size_t)cd * M + f], nrm * h[(size_t)rs * M + f]);
}

__global__ void k_gcn_fin(float* __restrict__ io, const float* __restrict__ h,
                          const float* __restrict__ dinv, const float* __restrict__ b,
                          int M, int n) {
  int i = blockIdx.x * blockDim.x + threadIdx.x;
  if (i >= n) return;
  int v = i / M, f = i % M;
  float dv = dinv[v];
  io[i] += dv * dv * h[i] + b[f];
}

// ---------------- final head ----------------
__global__ __launch_bounds__(256) void k_final(const float* __restrict__ pg, const float* __restrict__ tg,
                                               const float* __restrict__ g, const float* __restrict__ mw,
                                               const float* __restrict__ mb, float* __restrict__ outp) {
  int wv = threadIdx.x >> 6, ln = threadIdx.x & 63;
  int r = blockIdx.x * 4 + wv;
  const float* pr = pg + (size_t)r * 128;
  const float* tr = tg + (size_t)r * 128;
  float pa = pr[ln] * mw[ln] + pr[ln + 64] * mw[ln + 64];
  float t0 = tr[ln], t1 = tr[ln + 64];
  float s[GBN];
  #pragma unroll
  for (int gb = 0; gb < GBN; ++gb)
    s[gb] = g[gb * 128 + ln] * t0 + g[gb * 128 + 64 + ln] * t1;
  #pragma unroll
  for (int o = 32; o > 0; o >>= 1) {
    pa += __shfl_down(pa, o);
    #pragma unroll
    for (int gb = 0; gb < GBN; ++gb) s[gb] += __shfl_down(s[gb], o);
  }
  if (ln == 0) {
    float lg = pa + mb[0];
    #pragma unroll
    for (int gb = 0; gb < GBN; ++gb) lg = fmaf(s[gb], mw[128 + gb], lg);
    outp[r] = 1.0f / (1.0f + __expf(-lg));
  }
}

// ---------------- host launch ----------------
static inline int gdiv(long long n) { return (int)((n + 255) / 256); }

extern "C" void kernel_launch(void* const* d_in, const int* in_sizes, int n_in,
                              void* d_out, int out_size, void* d_ws, size_t ws_size,
                              hipStream_t stream) {
  const float* price  = (const float*)d_in[0];
  const float* gtrend = (const float*)d_in[1];
  const int*   p_ei   = (const int*)d_in[2];
  const float* p_w    = (const float*)d_in[3];
  const int*   t_ei   = (const int*)d_in[4];
  const float* t_w    = (const float*)d_in[5];
  const float* lpWih0 = (const float*)d_in[6];
  const float* lpWhh0 = (const float*)d_in[7];
  const float* lpBih0 = (const float*)d_in[8];
  const float* lpBhh0 = (const float*)d_in[9];
  const float* lpWih1 = (const float*)d_in[10];
  const float* lpWhh1 = (const float*)d_in[11];
  const float* lpBih1 = (const float*)d_in[12];
  const float* lpBhh1 = (const float*)d_in[13];
  const float* ltWih0 = (const float*)d_in[14];
  const float* ltWhh0 = (const float*)d_in[15];
  const float* ltBih0 = (const float*)d_in[16];
  const float* ltBhh0 = (const float*)d_in[17];
  const float* ltWih1 = (const float*)d_in[18];
  const float* ltWhh1 = (const float*)d_in[19];
  const float* ltBih1 = (const float*)d_in[20];
  const float* ltBhh1 = (const float*)d_in[21];
  const float* apW1 = (const float*)d_in[22];
  const float* apB1 = (const float*)d_in[23];
  const float* apW2 = (const float*)d_in[24];
  const float* apB2 = (const float*)d_in[25];
  const float* atW1 = (const float*)d_in[26];
  const float* atB1 = (const float*)d_in[27];
  const float* atW2 = (const float*)d_in[28];
  const float* atB2 = (const float*)d_in[29];
  const float* gp1W = (const float*)d_in[30];
  const float* gp1b = (const float*)d_in[31];
  const float* gp2W = (const float*)d_in[32];
  const float* gp2b = (const float*)d_in[33];
  const float* gt1W = (const float*)d_in[34];
  const float* gt1b = (const float*)d_in[35];
  const float* gt2W = (const float*)d_in[36];
  const float* gt2b = (const float*)d_in[37];
  const float* mlpW = (const float*)d_in[38];
  const float* mlpb = (const float*)d_in[39];

  float* ws = (float*)d_ws;
  float* outp = (float*)d_out;
  if (ws_size < (size_t)WS_END * sizeof(float)) return;

  // TC=32: h0S (33MB) + pre1 (135MB) stay L3-resident
  int TC = 0;
  for (int cand = 32; cand >= 8; cand >>= 1) {
    unsigned long long need = ((unsigned long long)H0S_O + 129ULL * cand * (2048ULL + 8192ULL)) * 4ULL;
    if ((unsigned long long)ws_size >= need) { TC = cand; break; }
  }
  if (TC == 0) return;  // ws proven >= 350 MB

  k_pack<<<gdiv(16384), 256, 0, stream>>>(lpWhh0, lpWhh0, 128, 128, 32, 4, (ushort*)(ws + N_P0));
  k_pack<<<gdiv(16384), 256, 0, stream>>>(lpWih1, lpWih1, 128, 128, 32, 4, (ushort*)(ws + N_P1I));
  k_pack<<<gdiv(16384), 256, 0, stream>>>(lpWhh1, lpWhh1, 128, 128, 32, 4, (ushort*)(ws + N_P1H));
  k_pack<<<gdiv(4096),  256, 0, stream>>>(apW1,   apW1,   128, 128,  8, 4, (ushort*)(ws + N_PA));
  k_pack<<<gdiv(16384), 256, 0, stream>>>(ltWhh0, ltWhh0, 128, 128, 32, 4, (ushort*)(ws + N_T0));
  k_pack<<<gdiv(16384), 256, 0, stream>>>(ltWih1, ltWih1, 128, 128, 32, 4, (ushort*)(ws + N_T1I));
  k_pack<<<gdiv(16384), 256, 0, stream>>>(ltWhh1, ltWhh1, 128, 128, 32, 4, (ushort*)(ws + N_T1H));
  k_pack<<<gdiv(4096),  256, 0, stream>>>(atW1,   atW1,   128, 128,  8, 4, (ushort*)(ws + N_TA));

  k_fill1<<<gdiv(NROW), 256, 0, stream>>>(ws + DINVP, NROW);
  k_deg<<<gdiv(EDG), 256, 0, stream>>>(p_ei + EDG, p_w, ws + DINVP, EDG);
  k_dinv<<<gdiv(NROW), 256, 0, stream>>>(ws + DINVP, NROW);
  k_fill1<<<gdiv(NROW), 256, 0, stream>>>(ws + DINVT, NROW);
  k_deg<<<gdiv(EDG), 256, 0, stream>>>(t_ei + EDG, t_w, ws + DINVT, EDG);
  k_dinv<<<gdiv(NROW), 256, 0, stream>>>(ws + DINVT, NROW);

  ushort* h0S = (ushort*)(ws + H0S_O);
  float*  pre1 = ws + H0S_O + (long long)129 * TC * 2048;
  {
    const int CH = TT / TC;
    const int nsub = TC / 4;
    for (int c = 0; c < CH; ++c) {
      k_pipe<<<194, 512, 0, stream>>>(price, gtrend, ws, h0S, ws + C0S_O,
                                      lpWih0, lpBih0, lpBhh0,
                                      ltWih0, ltBih0, ltBhh0,
                                      pre1, ws + XBUF, ws + GBUFO,
                                      ws + C1S_O, (ushort*)(ws + H1IMG_O), ws + SMST_O,
                                      ws + NUMS_O, ws + ACCOS_O,
                                      apB1, apW2, apB2, atB1, atW2, atB2,
                                      c * TC, TC,
                                      c == 0 ? 1 : 0, c == 1 ? 1 : 0,
                                      1, c > 0 ? 1 : 0);
      k_pre1<<<129 * nsub, 512, 0, stream>>>(h0S, ws, pre1,
                                             lpBih1, lpBhh1, ltBih1, ltBhh1,
                                             128, TC, nsub);
    }
    // drain: L1(CH-1)
    k_pipe<<<194, 512, 0, stream>>>(price, gtrend, ws, h0S, ws + C0S_O,
                                    lpWih0, lpBih0, lpBhh0,
                                    ltWih0, ltBih0, ltBhh0,
                                    pre1, ws + XBUF, ws + GBUFO,
                                    ws + C1S_O, (ushort*)(ws + H1IMG_O), ws + SMST_O,
                                    ws + NUMS_O, ws + ACCOS_O,
                                    apB1, apW2, apB2, atB1, atW2, atB2,
                                    0, TC, 0, CH == 1 ? 1 : 0, 0, 1);
  }

  // --- price graph ---
  k_lin<<<gdiv(NROW * 16), 256, 0, stream>>>(ws + XBUF, gp1W, ws + H16, 16, 128, NROW * 16);
  k_zero<<<gdiv(NROW * 16), 256, 0, stream>>>(ws + PG1, NROW * 16);
  k_scatter<<<gdiv((long long)EDG * 16), 256, 0, stream>>>(p_ei, p_ei + EDG, p_w, ws + DINVP,
                                                           ws + H16, ws + PG1, 16, (long long)EDG * 16);
  k_gcn_fin<<<gdiv(NROW * 16), 256, 0, stream>>>(ws + PG1, ws + H16, ws + DINVP, gp1b, 16, NROW * 16);
  k_lin<<<gdiv(NROW * 128), 256, 0, stream>>>(ws + PG1, gp2W, ws + H128, 128, 16, NROW * 128);
  k_zero<<<gdiv(NROW * 128), 256, 0, stream>>>(ws + PGB, NROW * 128);
  k_scatter<<<gdiv((long long)EDG * 128), 256, 0, stream>>>(p_ei, p_ei + EDG, p_w, ws + DINVP,
                                                            ws + H128, ws + PGB, 128, (long long)EDG * 128);
  k_gcn_fin<<<gdiv(NROW * 128), 256, 0, stream>>>(ws + PGB, ws + H128, ws + DINVP, gp2b, 128, NROW * 128);

  // --- trend graph (input is x) ---
  k_lin<<<gdiv(NROW * 16), 256, 0, stream>>>(ws + XBUF, gt1W, ws + H16, 16, 128, NROW * 16);
  k_zero<<<gdiv(NROW * 16), 256, 0, stream>>>(ws + TG1, NROW * 16);
  k_scatter<<<gdiv((long long)EDG * 16), 256, 0, stream>>>(t_ei, t_ei + EDG, t_w, ws + DINVT,
                                                           ws + H16, ws + TG1, 16, (long long)EDG * 16);
  k_gcn_fin<<<gdiv(NROW * 16), 256, 0, stream>>>(ws + TG1, ws + H16, ws + DINVT, gt1b, 16, NROW * 16);
  k_lin<<<gdiv(NROW * 128), 256, 0, stream>>>(ws + TG1, gt2W, ws + H128, 128, 16, NROW * 128);
  k_zero<<<gdiv(NROW * 128), 256, 0, stream>>>(ws + TGB, NROW * 128);
  k_scatter<<<gdiv((long long)EDG * 128), 256, 0, stream>>>(t_ei, t_ei + EDG, t_w, ws + DINVT,
                                                            ws + H128, ws + TGB, 128, (long long)EDG * 128);
  k_gcn_fin<<<gdiv(NROW * 128), 256, 0, stream>>>(ws + TGB, ws + H128, ws + DINVT, gt2b, 128, NROW * 128);

  // --- head ---
  k_final<<<512, 256, 0, stream>>>(ws + PGB, ws + TGB, ws + GBUFO, mlpW, mlpb, outp);
}

// Round 15
// 2062.980 us; speedup vs baseline: 1.7938x; 1.7938x over previous
//
#include <hip/hip_runtime.h>
#include <hip/hip_bf16.h>
#include <cstddef>

#define TT    256
#define NROW  2048
#define GBN   5
#define EDG   65536

using f32x4  = __attribute__((ext_vector_type(4))) float;
using bf16x8 = __attribute__((ext_vector_type(8))) short;

__device__ __forceinline__ void pinv(bf16x8& x) { asm volatile("" : "+v"(x)); }

__device__ __forceinline__ void barrier_lgkm() {
  asm volatile("s_waitcnt lgkmcnt(0)" ::: "memory");
  __builtin_amdgcn_s_barrier();
}

__device__ __forceinline__ float exp2fa(float x) { float r; asm("v_exp_f32 %0, %1" : "=v"(r) : "v"(x)); return r; }
__device__ __forceinline__ float rcpfa(float x)  { float r; asm("v_rcp_f32 %0, %1" : "=v"(r) : "v"(x)); return r; }
#define L2E 1.4426950408889634f
__device__ __forceinline__ float sigf(float x) { return rcpfa(1.0f + exp2fa(x * -L2E)); }
__device__ __forceinline__ float tanh_fast(float x) {
  float t = exp2fa(x * (-2.0f * L2E));
  return (1.0f - t) * rcpfa(1.0f + t);
}

// ---------------- workspace float offsets ----------------
enum : int {
  XBUF   = 425984,
  GBUFO  = 688128,
  DINVP  = 688768,
  DINVT  = 690816,
  H16    = 692864,
  PG1    = 725632,
  H128   = 758400,
  PGB    = 1020544,
  TG1    = 1282688,
  TGB    = 1315456,
  WS_END = 1577600
};

enum : int {
  N_P0   = 0,
  N_P1I  = 65536,
  N_P1H  = 131072,
  N_PA   = 196608,
  N_T0   = 212992,
  N_T1I  = 278528,
  N_T1H  = 344064,
  N_TA   = 409600
};

// state: L0 = 65 blocks x 32 rows (c0S 65*4096); L1 = 129 x 16 rows.
enum : long long {
  C0S_O   = 1577600,   // 65*4096
  C1S_O   = 1843840,   // 129*2048
  H1IMG_O = 2108032,   // 129*4096 ushort
  SMST_O  = 2372224,   // 129*32
  NUMS_O  = 2376352,
  ACCOS_O = 2640544,
  H0S_O   = 2904736    // DOUBLE-BUFFERED [2][65][TC][8192] ushort; pre1 follows
};

// LDS overlay; padded past 80KB so only ONE block fits per CU
struct __align__(16) SmemPipe {
  ushort a[2][4096];    // L0: h0 hi dbuf [tile*2048+idx]; L1: h1 hi (first 2048)
  ushort b[2][4096];
  float  x[5120];       // L0 xsa: [32 steps][32 rows][5]
  float  s[2][8][16];   // L1 sbuf
  float  pad[8192];     // occupancy limiter (~85KB)
};

// ---------------- weight fragment packing ----------------
__global__ void k_pack(const float* __restrict__ Wa, const float* __restrict__ Wb,
                       int K1, int K2, int NT, int KS, ushort* __restrict__ dst) {
  int t = blockIdx.x * blockDim.x + threadIdx.x;
  int total = KS * NT * 2 * 64;
  if (t >= total) return;
  int lane = t & 63;
  int part = (t >> 6) & 1;
  int rest = t >> 7;
  int nt = rest % NT, kk = rest / NT;
  int j = nt * 16 + (lane & 15);
  int kbase = kk * 32 + (lane >> 4) * 8;
  bf16x8 o;
  #pragma unroll
  for (int e = 0; e < 8; ++e) {
    int k = kbase + e;
    float x = (k < K1) ? Wa[(size_t)j * K1 + k] : Wb[(size_t)j * K2 + (k - K1)];
    __hip_bfloat16 hi = __float2bfloat16(x);
    ushort u;
    if (part == 0) {
      u = *(ushort*)&hi;
    } else {
      float lo = x - __bfloat162float(hi);
      __hip_bfloat16 lob = __float2bfloat16(lo);
      u = *(ushort*)&lob;
    }
    o[e] = (short)u;
  }
  ((bf16x8*)dst)[t] = o;
}

// ---------------- misc prep ----------------
__global__ void k_zero(float* __restrict__ p, int n) {
  int i = blockIdx.x * blockDim.x + threadIdx.x;
  if (i < n) p[i] = 0.0f;
}
__global__ void k_fill1(float* __restrict__ p, int n) {
  int i = blockIdx.x * blockDim.x + threadIdx.x;
  if (i < n) p[i] = 1.0f;
}
__global__ void k_deg(const int* __restrict__ col, const float* __restrict__ w,
                      float* __restrict__ deg, int n) {
  int i = blockIdx.x * blockDim.x + threadIdx.x;
  if (i < n) atomicAdd(&deg[col[i]], w[i]);
}
__global__ void k_dinv(float* __restrict__ deg, int n) {
  int i = blockIdx.x * blockDim.x + threadIdx.x;
  if (i < n) deg[i] = rsqrtf(deg[i]);
}

// =====================================================================
// Role A: layer-0 recurrence, 32 rows/block (65 blocks). Writes h0W
// (buffer c&1); restores handoff image from h0R (buffer (c-1)&1).
// =====================================================================
__device__ static void lstm0_body(
    SmemPipe* sm, int b,
    const float* __restrict__ price, const float* __restrict__ gtrend,
    const float* __restrict__ ws_ro, ushort* __restrict__ h0W,
    const ushort* __restrict__ h0R, float* __restrict__ c0S,
    const float* __restrict__ Wih0p, const float* __restrict__ bi0p, const float* __restrict__ bh0p,
    const float* __restrict__ Wih0t, const float* __restrict__ bi0t, const float* __restrict__ bh0t,
    int t0, int TCp, int first)
{
  const int tid = threadIdx.x;
  const int w = tid >> 6, l = tid & 63;
  const int lq = l >> 4, lr = l & 15;
  const int rb = lq * 4;
  const int kcol = w * 16 + lr;
  const bool isP = b < 64;
  const int R = isP ? 32 : GBN;
  const float* seq = isP ? (price + (size_t)b * 32 * (TT * 5)) : gtrend;
  const ushort* S0 = (const ushort*)(ws_ro + (isP ? N_P0 : N_T0));
  const float* Wih0 = isP ? Wih0p : Wih0t;
  const float* bi0 = isP ? bi0p : bi0t;
  const float* bh0 = isP ? bh0p : bh0t;

  auto h0hi = sm->a;
  auto h0lo = sm->b;
  float* xsa = sm->x;

  bf16x8 wh[4][4], wl[4][4];
  #pragma unroll
  for (int kk = 0; kk < 4; ++kk)
    #pragma unroll
    for (int g = 0; g < 4; ++g) {
      int blk = (kk * 32 + (w + 8 * g)) * 2;
      wh[kk][g] = ((const bf16x8*)S0)[(blk + 0) * 64 + l];
      wl[kk][g] = ((const bf16x8*)S0)[(blk + 1) * 64 + l];
      pinv(wh[kk][g]); pinv(wl[kk][g]);
    }
  float wih0r[4][5], bg0[4];
  #pragma unroll
  for (int g = 0; g < 4; ++g) {
    int j = kcol + 128 * g;
    bg0[g] = bi0[j] + bh0[j];
    #pragma unroll
    for (int k = 0; k < 5; ++k) wih0r[g][k] = Wih0[j * 5 + k];
  }

  const size_t bstr = (size_t)b * (size_t)TCp * 8192;
  float c0[2][4] = {{0, 0, 0, 0}, {0, 0, 0, 0}};

  for (int i = tid; i < TCp * 160; i += 512) {
    int tl = i / 160, rem = i % 160, r = rem / 5, k = rem % 5;
    xsa[tl * 160 + rem] = (r < R) ? seq[(size_t)r * (TT * 5) + (size_t)(t0 + tl) * 5 + k] : 0.0f;
  }
  if (first) {
    for (int i = tid; i < 4096; i += 512) { h0hi[0][i] = 0; h0lo[0][i] = 0; }
  } else {
    const size_t lb = bstr + (size_t)(TCp - 1) * 8192;
    *(uint4*)&h0hi[0][8 * tid] = *(const uint4*)&h0R[lb + 8 * tid];
    *(uint4*)&h0lo[0][8 * tid] = *(const uint4*)&h0R[lb + 4096 + 8 * tid];
    #pragma unroll
    for (int t = 0; t < 2; ++t)
      #pragma unroll
      for (int reg = 0; reg < 4; ++reg)
        c0[t][reg] = c0S[(size_t)b * 4096 + (size_t)(t * 16 + rb + reg) * 128 + kcol];
  }
  __syncthreads();

  const int kkhi = (kcol >> 3) & 3;
  const int eo = kcol & 7;
  const int b0w = rb + 16 * kkhi;
  const int kkw = kcol >> 5;
  int wro[4];
  #pragma unroll
  for (int reg = 0; reg < 4; ++reg) wro[reg] = kkw * 512 + (b0w + (reg ^ lq)) * 8 + eo;
  const int rdo = (l ^ ((l >> 2) & 3)) * 8;

  int cur = 0;
  for (int tl = 0; tl < TCp; ++tl) {
    const int nxt = cur ^ 1;
    if (tl > 0) {
      *(uint4*)&h0W[bstr + (size_t)(tl - 1) * 8192 + 8 * tid] = *(const uint4*)&h0hi[cur][8 * tid];
      *(uint4*)&h0W[bstr + (size_t)(tl - 1) * 8192 + 4096 + 8 * tid] = *(const uint4*)&h0lo[cur][8 * tid];
    }

    f32x4 acc[2][4];
    #pragma unroll
    for (int t = 0; t < 2; ++t)
      #pragma unroll
      for (int g = 0; g < 4; ++g) acc[t][g] = (f32x4){bg0[g], bg0[g], bg0[g], bg0[g]};
    #pragma unroll
    for (int k = 0; k < 5; ++k) {
      float xv[2][4];
      #pragma unroll
      for (int t = 0; t < 2; ++t)
        #pragma unroll
        for (int reg = 0; reg < 4; ++reg)
          xv[t][reg] = xsa[tl * 160 + (t * 16 + rb + reg) * 5 + k];
      #pragma unroll
      for (int t = 0; t < 2; ++t)
        #pragma unroll
        for (int g = 0; g < 4; ++g)
          #pragma unroll
          for (int reg = 0; reg < 4; ++reg)
            acc[t][g][reg] = fmaf(xv[t][reg], wih0r[g][k], acc[t][g][reg]);
    }
    #pragma unroll
    for (int kk = 0; kk < 4; ++kk) {
      bf16x8 ah0 = *(const bf16x8*)&h0hi[cur][kk * 512 + rdo];
      bf16x8 al0 = *(const bf16x8*)&h0lo[cur][kk * 512 + rdo];
      bf16x8 ah1 = *(const bf16x8*)&h0hi[cur][2048 + kk * 512 + rdo];
      bf16x8 al1 = *(const bf16x8*)&h0lo[cur][2048 + kk * 512 + rdo];
      #pragma unroll
      for (int g = 0; g < 4; ++g) {
        acc[0][g] = __builtin_amdgcn_mfma_f32_16x16x32_bf16(ah0, wh[kk][g], acc[0][g], 0, 0, 0);
        acc[0][g] = __builtin_amdgcn_mfma_f32_16x16x32_bf16(al0, wh[kk][g], acc[0][g], 0, 0, 0);
        acc[0][g] = __builtin_amdgcn_mfma_f32_16x16x32_bf16(ah0, wl[kk][g], acc[0][g], 0, 0, 0);
        acc[1][g] = __builtin_amdgcn_mfma_f32_16x16x32_bf16(ah1, wh[kk][g], acc[1][g], 0, 0, 0);
        acc[1][g] = __builtin_amdgcn_mfma_f32_16x16x32_bf16(al1, wh[kk][g], acc[1][g], 0, 0, 0);
        acc[1][g] = __builtin_amdgcn_mfma_f32_16x16x32_bf16(ah1, wl[kk][g], acc[1][g], 0, 0, 0);
      }
    }
    #pragma unroll
    for (int t = 0; t < 2; ++t)
      #pragma unroll
      for (int reg = 0; reg < 4; ++reg) {
        float gi = acc[t][0][reg], gf = acc[t][1][reg], gg = acc[t][2][reg], go = acc[t][3][reg];
        float c = sigf(gf) * c0[t][reg] + sigf(gi) * tanh_fast(gg);
        c0[t][reg] = c;
        float h = sigf(go) * tanh_fast(c);
        __hip_bfloat16 hb = __float2bfloat16(h);
        float lo = h - __bfloat162float(hb);
        __hip_bfloat16 lb = __float2bfloat16(lo);
        h0hi[nxt][t * 2048 + wro[reg]] = *(ushort*)&hb;
        h0lo[nxt][t * 2048 + wro[reg]] = *(ushort*)&lb;
      }
    barrier_lgkm();
    cur = nxt;
  }
  *(uint4*)&h0W[bstr + (size_t)(TCp - 1) * 8192 + 8 * tid] = *(const uint4*)&h0hi[cur][8 * tid];
  *(uint4*)&h0W[bstr + (size_t)(TCp - 1) * 8192 + 4096 + 8 * tid] = *(const uint4*)&h0lo[cur][8 * tid];

  #pragma unroll
  for (int t = 0; t < 2; ++t)
    #pragma unroll
    for (int reg = 0; reg < 4; ++reg)
      c0S[(size_t)b * 4096 + (size_t)(t * 16 + rb + reg) * 128 + kcol] = c0[t][reg];
}

// =====================================================================
// Role B: FUSED pre1 pre-phase (reads h0R = chunk c-1's 32-row image,
// writes own pre1 slice, vmcnt(0)) + layer-1 recurrence (16 rows,
// pinned weights) + deferred online softmax. 1 barrier/step.
// =====================================================================
__device__ static void lstm1_body(
    SmemPipe* sm, int b16,
    const ushort* __restrict__ h0R, float* __restrict__ pre1, const float* __restrict__ ws_ro,
    float* __restrict__ xout, float* __restrict__ gout,
    float* __restrict__ c1S, ushort* __restrict__ h1imgS, float* __restrict__ smS,
    float* __restrict__ numS, float* __restrict__ accOS,
    const float* __restrict__ bi1p, const float* __restrict__ bh1p,
    const float* __restrict__ apB1, const float* __restrict__ apW2, const float* __restrict__ apB2,
    const float* __restrict__ bi1t, const float* __restrict__ bh1t,
    const float* __restrict__ atB1, const float* __restrict__ atW2, const float* __restrict__ atB2,
    int TCp, int first)
{
  const int tid = threadIdx.x;
  const int w = tid >> 6, l = tid & 63;
  const int lq = l >> 4, lr = l & 15;
  const int rb = lq * 4;
  const int kcol = w * 16 + lr;
  const bool isP = b16 < 128;
  const int R = isP ? 16 : GBN;
  const ushort* S1I = (const ushort*)(ws_ro + (isP ? N_P1I : N_T1I));
  const ushort* S1H = (const ushort*)(ws_ro + (isP ? N_P1H : N_T1H));
  const ushort* SA  = (const ushort*)(ws_ro + (isP ? N_PA : N_TA));
  const float* bi1 = isP ? bi1p : bi1t;
  const float* bh1 = isP ? bh1p : bh1t;
  const float* b1ap = isP ? apB1 : atB1;
  const float* w2p  = isP ? apW2 : atW2;
  const float  b2v  = isP ? apB2[0] : atB2[0];

  auto h1hi = sm->a;
  auto h1lo = sm->b;
  auto sbuf = sm->s;

  const int rdo = (l ^ ((l >> 2) & 3)) * 8;
  float* pblk = pre1 + (size_t)b16 * TCp * 8192;

  // ---- fused pre-phase: pre1[tl] = h0(c-1)[tl] @ Wih1^T + b1 ----
  {
    const int b32 = b16 >> 1, tile = b16 & 1;   // b16==128 -> b32=64, tile=0
    const size_t bstr32 = (size_t)b32 * (size_t)TCp * 8192;
    float bg1[4];
    #pragma unroll
    for (int g = 0; g < 4; ++g) bg1[g] = bi1[kcol + 128 * g] + bh1[kcol + 128 * g];
    for (int g0 = 0; g0 < TCp; g0 += 2) {
      f32x4 pacc[2][4];
      #pragma unroll
      for (int ts = 0; ts < 2; ++ts)
        #pragma unroll
        for (int g = 0; g < 4; ++g) pacc[ts][g] = (f32x4){bg1[g], bg1[g], bg1[g], bg1[g]};
      #pragma unroll
      for (int kk = 0; kk < 4; ++kk) {
        bf16x8 bh_[4], bl_[4];
        #pragma unroll
        for (int g = 0; g < 4; ++g) {
          int blk = (kk * 32 + (w + 8 * g)) * 2;
          bh_[g] = ((const bf16x8*)S1I)[(blk + 0) * 64 + l];
          bl_[g] = ((const bf16x8*)S1I)[(blk + 1) * 64 + l];
        }
        #pragma unroll
        for (int ts = 0; ts < 2; ++ts) {
          const size_t tb = bstr32 + (size_t)(g0 + ts) * 8192 + tile * 2048 + kk * 512 + rdo;
          bf16x8 ah = *(const bf16x8*)&h0R[tb];
          bf16x8 al = *(const bf16x8*)&h0R[tb + 4096];
          #pragma unroll
          for (int g = 0; g < 4; ++g) {
            pacc[ts][g] = __builtin_amdgcn_mfma_f32_16x16x32_bf16(ah, bh_[g], pacc[ts][g], 0, 0, 0);
            pacc[ts][g] = __builtin_amdgcn_mfma_f32_16x16x32_bf16(al, bh_[g], pacc[ts][g], 0, 0, 0);
            pacc[ts][g] = __builtin_amdgcn_mfma_f32_16x16x32_bf16(ah, bl_[g], pacc[ts][g], 0, 0, 0);
          }
        }
      }
      #pragma unroll
      for (int ts = 0; ts < 2; ++ts)
        #pragma unroll
        for (int g = 0; g < 4; ++g)
          *(f32x4*)&pblk[(size_t)(g0 + ts) * 8192 + (size_t)tid * 16 + g * 4] = pacc[ts][g];
    }
    asm volatile("s_waitcnt vmcnt(0)" ::: "memory");   // own stores retired before readback
  }

  // ---- resident weights (pinned) ----
  bf16x8 hh[4][4], hl[4][4];
  #pragma unroll
  for (int kk = 0; kk < 4; ++kk)
    #pragma unroll
    for (int g = 0; g < 4; ++g) {
      int blk = (kk * 32 + (w + 8 * g)) * 2;
      hh[kk][g] = ((const bf16x8*)S1H)[(blk + 0) * 64 + l];
      hl[kk][g] = ((const bf16x8*)S1H)[(blk + 1) * 64 + l];
      pinv(hh[kk][g]); pinv(hl[kk][g]);
    }
  bf16x8 wa[4], wal[4];
  #pragma unroll
  for (int kk = 0; kk < 4; ++kk) {
    wa[kk]  = ((const bf16x8*)SA)[((kk * 8 + w) * 2 + 0) * 64 + l];
    wal[kk] = ((const bf16x8*)SA)[((kk * 8 + w) * 2 + 1) * 64 + l];
    pinv(wa[kk]); pinv(wal[kk]);
  }
  const float w2r = w2p[kcol], b1ar = b1ap[kcol];

  float c1[4] = {0, 0, 0, 0}, h1r[4] = {0, 0, 0, 0}, h1r_prev[4];
  float num[4] = {0, 0, 0, 0}, accO[4] = {0, 0, 0, 0};
  float m_run[4], den_r[4];

  if (first) {
    for (int i = tid; i < 2048; i += 512) { h1hi[0][i] = 0; h1lo[0][i] = 0; }
    #pragma unroll
    for (int reg = 0; reg < 4; ++reg) { m_run[reg] = -1e30f; den_r[reg] = 0.0f; }
  } else {
    const size_t ib = (size_t)b16 * 4096;
    *(uint2*)&h1hi[0][4 * tid] = *(const uint2*)&h1imgS[ib + 4 * tid];
    *(uint2*)&h1lo[0][4 * tid] = *(const uint2*)&h1imgS[ib + 2048 + 4 * tid];
    const size_t sb = (size_t)b16 * 2048;
    #pragma unroll
    for (int reg = 0; reg < 4; ++reg) {
      size_t o = sb + (size_t)(rb + reg) * 128 + kcol;
      c1[reg] = c1S[o];
      num[reg] = numS[o];
      accO[reg] = accOS[o];
      m_run[reg] = smS[(size_t)b16 * 32 + (size_t)(rb + reg) * 2];
      den_r[reg] = smS[(size_t)b16 * 32 + (size_t)(rb + reg) * 2 + 1];
    }
  }
  __syncthreads();

  const int kkhi = (kcol >> 3) & 3;
  const int eo = kcol & 7;
  const int b0w = rb + 16 * kkhi;
  const int kkw = kcol >> 5;
  int wro[4];
  #pragma unroll
  for (int reg = 0; reg < 4; ++reg) wro[reg] = kkw * 512 + (b0w + (reg ^ lq)) * 8 + eo;

  const float* pbase = pblk + (size_t)tid * 16;

  f32x4 pnext[4];
  #pragma unroll
  for (int g = 0; g < 4; ++g) pnext[g] = *(const f32x4*)&pbase[g * 4];

  int cur = 0;
  for (int tl = 0; tl < TCp; ++tl) {
    const int nxt = cur ^ 1;
    f32x4 acc[4];
    #pragma unroll
    for (int g = 0; g < 4; ++g) acc[g] = pnext[g];
    if (tl + 1 < TCp) {
      #pragma unroll
      for (int g = 0; g < 4; ++g)
        pnext[g] = *(const f32x4*)&pbase[(size_t)(tl + 1) * 8192 + g * 4];
    }

    #pragma unroll
    for (int kk = 0; kk < 4; ++kk) {
      bf16x8 ah = *(const bf16x8*)&h1hi[cur][kk * 512 + rdo];
      bf16x8 al = *(const bf16x8*)&h1lo[cur][kk * 512 + rdo];
      #pragma unroll
      for (int g = 0; g < 4; ++g) {
        acc[g] = __builtin_amdgcn_mfma_f32_16x16x32_bf16(ah, hh[kk][g], acc[g], 0, 0, 0);
        acc[g] = __builtin_amdgcn_mfma_f32_16x16x32_bf16(al, hh[kk][g], acc[g], 0, 0, 0);
        acc[g] = __builtin_amdgcn_mfma_f32_16x16x32_bf16(ah, hl[kk][g], acc[g], 0, 0, 0);
      }
    }
    #pragma unroll
    for (int reg = 0; reg < 4; ++reg) {
      h1r_prev[reg] = h1r[reg];
      float gi = acc[0][reg], gf = acc[1][reg], gg = acc[2][reg], go = acc[3][reg];
      float c = sigf(gf) * c1[reg] + sigf(gi) * tanh_fast(gg);
      c1[reg] = c;
      float h = sigf(go) * tanh_fast(c);
      h1r[reg] = h;
      __hip_bfloat16 hb = __float2bfloat16(h);
      float lo = h - __bfloat162float(hb);
      __hip_bfloat16 lb = __float2bfloat16(lo);
      h1hi[nxt][wro[reg]] = *(ushort*)&hb;
      h1lo[nxt][wro[reg]] = *(ushort*)&lb;
    }
    barrier_lgkm();

    if (tl > 0) {
      const int pb = (tl - 1) & 1;
      #pragma unroll
      for (int reg = 0; reg < 4; ++reg) {
        float s = b2v;
        #pragma unroll
        for (int ww = 0; ww < 8; ++ww) s += sbuf[pb][ww][rb + reg];
        float m0 = m_run[reg];
        float nm = fmaxf(m0, s);
        float e = exp2fa((s - nm) * L2E), sc = exp2fa((m0 - nm) * L2E);
        float d = den_r[reg] * sc + e;
        m_run[reg] = nm; den_r[reg] = d;
        num[reg] = num[reg] * sc + e * h1r_prev[reg];
        accO[reg] = fmaf(num[reg], rcpfa(d), accO[reg]);
      }
    }

    f32x4 aa = (f32x4){b1ar, b1ar, b1ar, b1ar};
    #pragma unroll
    for (int kk = 0; kk < 4; ++kk) {
      bf16x8 ah = *(const bf16x8*)&h1hi[nxt][kk * 512 + rdo];
      bf16x8 al = *(const bf16x8*)&h1lo[nxt][kk * 512 + rdo];
      aa = __builtin_amdgcn_mfma_f32_16x16x32_bf16(ah, wa[kk], aa, 0, 0, 0);
      aa = __builtin_amdgcn_mfma_f32_16x16x32_bf16(al, wa[kk], aa, 0, 0, 0);
      aa = __builtin_amdgcn_mfma_f32_16x16x32_bf16(ah, wal[kk], aa, 0, 0, 0);
    }
    float p[4];
    #pragma unroll
    for (int reg = 0; reg < 4; ++reg) p[reg] = tanh_fast(aa[reg]) * w2r;
    #pragma unroll
    for (int m = 1; m < 16; m <<= 1) {
      #pragma unroll
      for (int reg = 0; reg < 4; ++reg) p[reg] += __shfl_xor(p[reg], m);
    }
    if (lr == 0) {
      #pragma unroll
      for (int reg = 0; reg < 4; ++reg) sbuf[tl & 1][w][rb + reg] = p[reg];
    }
    cur = nxt;
  }
  barrier_lgkm();
  {
    const int pb = (TCp - 1) & 1;
    #pragma unroll
    for (int reg = 0; reg < 4; ++reg) {
      float s = b2v;
      #pragma unroll
      for (int ww = 0; ww < 8; ++ww) s += sbuf[pb][ww][rb + reg];
      float m0 = m_run[reg];
      float nm = fmaxf(m0, s);
      float e = exp2fa((s - nm) * L2E), sc = exp2fa((m0 - nm) * L2E);
      float d = den_r[reg] * sc + e;
      m_run[reg] = nm; den_r[reg] = d;
      num[reg] = num[reg] * sc + e * h1r[reg];
      accO[reg] = fmaf(num[reg], rcpfa(d), accO[reg]);
    }
  }

  {
    const size_t ib = (size_t)b16 * 4096;
    *(uint2*)&h1imgS[ib + 4 * tid] = *(const uint2*)&h1hi[cur][4 * tid];
    *(uint2*)&h1imgS[ib + 2048 + 4 * tid] = *(const uint2*)&h1lo[cur][4 * tid];
    const size_t sb = (size_t)b16 * 2048;
    #pragma unroll
    for (int reg = 0; reg < 4; ++reg) {
      size_t o = sb + (size_t)(rb + reg) * 128 + kcol;
      c1S[o] = c1[reg];
      numS[o] = num[reg];
      accOS[o] = accO[reg];
    }
    if (w == 0 && lr == 0) {
      #pragma unroll
      for (int reg = 0; reg < 4; ++reg) {
        smS[(size_t)b16 * 32 + (size_t)(rb + reg) * 2] = m_run[reg];
        smS[(size_t)b16 * 32 + (size_t)(rb + reg) * 2 + 1] = den_r[reg];
      }
    }
  }

  float* dstx = isP ? (xout + (size_t)b16 * 16 * 128) : gout;
  #pragma unroll
  for (int reg = 0; reg < 4; ++reg) {
    int r = rb + reg;
    if (r < R) dstx[(size_t)r * 128 + kcol] = accO[reg];
  }
}

// =====================================================================
// Fused pipeline: blocks 0..64 = L0(c) 32-row; 65..193 = L1(c-1) 16-row
// with fused pre1. 194 blocks, LDS-forced 1 block/CU.
// =====================================================================
__global__ __launch_bounds__(512, 2) void k_pipe(
    const float* __restrict__ price, const float* __restrict__ gtrend,
    const float* __restrict__ ws_ro, ushort* __restrict__ h0W, const ushort* __restrict__ h0R,
    float* __restrict__ c0S,
    const float* __restrict__ Wih0p, const float* __restrict__ bi0p, const float* __restrict__ bh0p,
    const float* __restrict__ Wih0t, const float* __restrict__ bi0t, const float* __restrict__ bh0t,
    float* __restrict__ pre1,
    float* __restrict__ xout, float* __restrict__ gout,
    float* __restrict__ c1S, ushort* __restrict__ h1imgS, float* __restrict__ smS,
    float* __restrict__ numS, float* __restrict__ accOS,
    const float* __restrict__ bi1p, const float* __restrict__ bh1p,
    const float* __restrict__ apB1, const float* __restrict__ apW2, const float* __restrict__ apB2,
    const float* __restrict__ bi1t, const float* __restrict__ bh1t,
    const float* __restrict__ atB1, const float* __restrict__ atW2, const float* __restrict__ atB2,
    int t0A, int TCp, int firstA, int firstB, int doA, int doB)
{
  __shared__ SmemPipe sm;
  const int bid = blockIdx.x;
  if (bid < 65) {
    if (doA)
      lstm0_body(&sm, bid, price, gtrend, ws_ro, h0W, h0R, c0S,
                 Wih0p, bi0p, bh0p, Wih0t, bi0t, bh0t, t0A, TCp, firstA);
  } else {
    if (doB)
      lstm1_body(&sm, bid - 65, h0R, pre1, ws_ro, xout, gout,
                 c1S, h1imgS, smS, numS, accOS,
                 bi1p, bh1p, apB1, apW2, apB2,
                 bi1t, bh1t, atB1, atW2, atB2, TCp, firstB);
  }
}

// ---------------- GCN kernels ----------------
__global__ void k_lin(const float* __restrict__ x, const float* __restrict__ W,
                      float* __restrict__ h, int M, int K, int n) {
  int i = blockIdx.x * blockDim.x + threadIdx.x;
  if (i >= n) return;
  int r = i / M, m = i % M;
  const float* xr = x + (size_t)r * K;
  const float* wm = W + (size_t)m * K;
  float a = 0.f;
  for (int k = 0; k < K; ++k) a = fmaf(xr[k], wm[k], a);
  h[i] = a;
}

__global__ void k_scatter(const int* __restrict__ rowi, const int* __restrict__ coli,
                          const float* __restrict__ w, const float* __restrict__ dinv,
                          const float* __restrict__ h, float* __restrict__ outp,
                          int M, long long n) {
  long long i = (long long)blockIdx.x * blockDim.x + threadIdx.x;
  if (i >= n) return;
  int e = (int)(i / M), f = (int)(i % M);
  int rs = rowi[e], cd = coli[e];
  float nrm = dinv[rs] * w[e] * dinv[cd];
  atomicAdd(&outp[(size_t)cd * M + f], nrm * h[(size_t)rs * M + f]);
}

__global__ void k_gcn_fin(float* __restrict__ io, const float* __restrict__ h,
                          const float* __restrict__ dinv, const float* __restrict__ b,
                          int M, int n) {
  int i = blockIdx.x * blockDim.x + threadIdx.x;
  if (i >= n) return;
  int v = i / M, f = i % M;
  float dv = dinv[v];
  io[i] += dv * dv * h[i] + b[f];
}

// ---------------- final head ----------------
__global__ __launch_bounds__(256) void k_final(const float* __restrict__ pg, const float* __restrict__ tg,
                                               const float* __restrict__ g, const float* __restrict__ mw,
                                               const float* __restrict__ mb, float* __restrict__ outp) {
  int wv = threadIdx.x >> 6, ln = threadIdx.x & 63;
  int r = blockIdx.x * 4 + wv;
  const float* pr = pg + (size_t)r * 128;
  const float* tr = tg + (size_t)r * 128;
  float pa = pr[ln] * mw[ln] + pr[ln + 64] * mw[ln + 64];
  float t0 = tr[ln], t1 = tr[ln + 64];
  float s[GBN];
  #pragma unroll
  for (int gb = 0; gb < GBN; ++gb)
    s[gb] = g[gb * 128 + ln] * t0 + g[gb * 128 + 64 + ln] * t1;
  #pragma unroll
  for (int o = 32; o > 0; o >>= 1) {
    pa += __shfl_down(pa, o);
    #pragma unroll
    for (int gb = 0; gb < GBN; ++gb) s[gb] += __shfl_down(s[gb], o);
  }
  if (ln == 0) {
    float lg = pa + mb[0];
    #pragma unroll
    for (int gb = 0; gb < GBN; ++gb) lg = fmaf(s[gb], mw[128 + gb], lg);
    outp[r] = 1.0f / (1.0f + __expf(-lg));
  }
}

// ---------------- host launch ----------------
static inline int gdiv(long long n) { return (int)((n + 255) / 256); }

extern "C" void kernel_launch(void* const* d_in, const int* in_sizes, int n_in,
                              void* d_out, int out_size, void* d_ws, size_t ws_size,
                              hipStream_t stream) {
  const float* price  = (const float*)d_in[0];
  const float* gtrend = (const float*)d_in[1];
  const int*   p_ei   = (const int*)d_in[2];
  const float* p_w    = (const float*)d_in[3];
  const int*   t_ei   = (const int*)d_in[4];
  const float* t_w    = (const float*)d_in[5];
  const float* lpWih0 = (const float*)d_in[6];
  const float* lpWhh0 = (const float*)d_in[7];
  const float* lpBih0 = (const float*)d_in[8];
  const float* lpBhh0 = (const float*)d_in[9];
  const float* lpWih1 = (const float*)d_in[10];
  const float* lpWhh1 = (const float*)d_in[11];
  const float* lpBih1 = (const float*)d_in[12];
  const float* lpBhh1 = (const float*)d_in[13];
  const float* ltWih0 = (const float*)d_in[14];
  const float* ltWhh0 = (const float*)d_in[15];
  const float* ltBih0 = (const float*)d_in[16];
  const float* ltBhh0 = (const float*)d_in[17];
  const float* ltWih1 = (const float*)d_in[18];
  const float* ltWhh1 = (const float*)d_in[19];
  const float* ltBih1 = (const float*)d_in[20];
  const float* ltBhh1 = (const float*)d_in[21];
  const float* apW1 = (const float*)d_in[22];
  const float* apB1 = (const float*)d_in[23];
  const float* apW2 = (const float*)d_in[24];
  const float* apB2 = (const float*)d_in[25];
  const float* atW1 = (const float*)d_in[26];
  const float* atB1 = (const float*)d_in[27];
  const float* atW2 = (const float*)d_in[28];
  const float* atB2 = (const float*)d_in[29];
  const float* gp1W = (const float*)d_in[30];
  const float* gp1b = (const float*)d_in[31];
  const float* gp2W = (const float*)d_in[32];
  const float* gp2b = (const float*)d_in[33];
  const float* gt1W = (const float*)d_in[34];
  const float* gt1b = (const float*)d_in[35];
  const float* gt2W = (const float*)d_in[36];
  const float* gt2b = (const float*)d_in[37];
  const float* mlpW = (const float*)d_in[38];
  const float* mlpb = (const float*)d_in[39];

  float* ws = (float*)d_ws;
  float* outp = (float*)d_out;
  if (ws_size < (size_t)WS_END * sizeof(float)) return;

  // TC: double-buffered h0S (2 x 65*TC*4096 f) + pre1 (129*TC*8192 f)
  int TC = 0;
  for (int cand = 32; cand >= 8; cand >>= 1) {
    unsigned long long need = ((unsigned long long)H0S_O +
                               2ULL * 65 * cand * 4096ULL + 129ULL * cand * 8192ULL) * 4ULL;
    if ((unsigned long long)ws_size >= need) { TC = cand; break; }
  }
  if (TC == 0) return;  // ws proven >= 180 MB (TC=16 needs 113 MB)

  k_pack<<<gdiv(16384), 256, 0, stream>>>(lpWhh0, lpWhh0, 128, 128, 32, 4, (ushort*)(ws + N_P0));
  k_pack<<<gdiv(16384), 256, 0, stream>>>(lpWih1, lpWih1, 128, 128, 32, 4, (ushort*)(ws + N_P1I));
  k_pack<<<gdiv(16384), 256, 0, stream>>>(lpWhh1, lpWhh1, 128, 128, 32, 4, (ushort*)(ws + N_P1H));
  k_pack<<<gdiv(4096),  256, 0, stream>>>(apW1,   apW1,   128, 128,  8, 4, (ushort*)(ws + N_PA));
  k_pack<<<gdiv(16384), 256, 0, stream>>>(ltWhh0, ltWhh0, 128, 128, 32, 4, (ushort*)(ws + N_T0));
  k_pack<<<gdiv(16384), 256, 0, stream>>>(ltWih1, ltWih1, 128, 128, 32, 4, (ushort*)(ws + N_T1I));
  k_pack<<<gdiv(16384), 256, 0, stream>>>(ltWhh1, ltWhh1, 128, 128, 32, 4, (ushort*)(ws + N_T1H));
  k_pack<<<gdiv(4096),  256, 0, stream>>>(atW1,   atW1,   128, 128,  8, 4, (ushort*)(ws + N_TA));

  k_fill1<<<gdiv(NROW), 256, 0, stream>>>(ws + DINVP, NROW);
  k_deg<<<gdiv(EDG), 256, 0, stream>>>(p_ei + EDG, p_w, ws + DINVP, EDG);
  k_dinv<<<gdiv(NROW), 256, 0, stream>>>(ws + DINVP, NROW);
  k_fill1<<<gdiv(NROW), 256, 0, stream>>>(ws + DINVT, NROW);
  k_deg<<<gdiv(EDG), 256, 0, stream>>>(t_ei + EDG, t_w, ws + DINVT, EDG);
  k_dinv<<<gdiv(NROW), 256, 0, stream>>>(ws + DINVT, NROW);

  ushort* h0S0 = (ushort*)(ws + H0S_O);
  ushort* h0S1 = h0S0 + (size_t)65 * TC * 8192;
  float*  pre1 = ws + H0S_O + 2LL * 65 * TC * 4096;
  {
    const int CH = TT / TC;
    for (int c = 0; c < CH; ++c) {
      ushort* hA = (c & 1) ? h0S1 : h0S0;
      ushort* hB = (c & 1) ? h0S0 : h0S1;   // = buffer (c-1)&1
      k_pipe<<<194, 512, 0, stream>>>(price, gtrend, ws, hA, hB, ws + C0S_O,
                                      lpWih0, lpBih0, lpBhh0,
                                      ltWih0, ltBih0, ltBhh0,
                                      pre1, ws + XBUF, ws + GBUFO,
                                      ws + C1S_O, (ushort*)(ws + H1IMG_O), ws + SMST_O,
                                      ws + NUMS_O, ws + ACCOS_O,
                                      lpBih1, lpBhh1, apB1, apW2, apB2,
                                      ltBih1, ltBhh1, atB1, atW2, atB2,
                                      c * TC, TC,
                                      c == 0 ? 1 : 0, c == 1 ? 1 : 0,
                                      1, c > 0 ? 1 : 0);
    }
    // drain: L1(CH-1) reads buffer (CH-1)&1
    ushort* hB = ((CH - 1) & 1) ? h0S1 : h0S0;
    k_pipe<<<194, 512, 0, stream>>>(price, gtrend, ws, h0S0, hB, ws + C0S_O,
                                    lpWih0, lpBih0, lpBhh0,
                                    ltWih0, ltBih0, ltBhh0,
                                    pre1, ws + XBUF, ws + GBUFO,
                                    ws + C1S_O, (ushort*)(ws + H1IMG_O), ws + SMST_O,
                                    ws + NUMS_O, ws + ACCOS_O,
                                    lpBih1, lpBhh1, apB1, apW2, apB2,
                                    ltBih1, ltBhh1, atB1, atW2, atB2,
                                    0, TC, 0, CH == 1 ? 1 : 0, 0, 1);
  }

  // --- price graph ---
  k_lin<<<gdiv(NROW * 16), 256, 0, stream>>>(ws + XBUF, gp1W, ws + H16, 16, 128, NROW * 16);
  k_zero<<<gdiv(NROW * 16), 256, 0, stream>>>(ws + PG1, NROW * 16);
  k_scatter<<<gdiv((long long)EDG * 16), 256, 0, stream>>>(p_ei, p_ei + EDG, p_w, ws + DINVP,
                                                           ws + H16, ws + PG1, 16, (long long)EDG * 16);
  k_gcn_fin<<<gdiv(NROW * 16), 256, 0, stream>>>(ws + PG1, ws + H16, ws + DINVP, gp1b, 16, NROW * 16);
  k_lin<<<gdiv(NROW * 128), 256, 0, stream>>>(ws + PG1, gp2W, ws + H128, 128, 16, NROW * 128);
  k_zero<<<gdiv(NROW * 128), 256, 0, stream>>>(ws + PGB, NROW * 128);
  k_scatter<<<gdiv((long long)EDG * 128), 256, 0, stream>>>(p_ei, p_ei + EDG, p_w, ws + DINVP,
                                                            ws + H128, ws + PGB, 128, (long long)EDG * 128);
  k_gcn_fin<<<gdiv(NROW * 128), 256, 0, stream>>>(ws + PGB, ws + H128, ws + DINVP, gp2b, 128, NROW * 128);

  // --- trend graph (input is x) ---
  k_lin<<<gdiv(NROW * 16), 256, 0, stream>>>(ws + XBUF, gt1W, ws + H16, 16, 128, NROW * 16);
  k_zero<<<gdiv(NROW * 16), 256, 0, stream>>>(ws + TG1, NROW * 16);
  k_scatter<<<gdiv((long long)EDG * 16), 256, 0, stream>>>(t_ei, t_ei + EDG, t_w, ws + DINVT,
                                                           ws + H16, ws + TG1, 16, (long long)EDG * 16);
  k_gcn_fin<<<gdiv(NROW * 16), 256, 0, stream>>>(ws + TG1, ws + H16, ws + DINVT, gt1b, 16, NROW * 16);
  k_lin<<<gdiv(NROW * 128), 256, 0, stream>>>(ws + TG1, gt2W, ws + H128, 128, 16, NROW * 128);
  k_zero<<<gdiv(NROW * 128), 256, 0, stream>>>(ws + TGB, NROW * 128);
  k_scatter<<<gdiv((long long)EDG * 128), 256, 0, stream>>>(t_ei, t_ei + EDG, t_w, ws + DINVT,
                                                            ws + H128, ws + TGB, 128, (long long)EDG * 128);
  k_gcn_fin<<<gdiv(NROW * 128), 256, 0, stream>>>(ws + TGB, ws + H128, ws + DINVT, gt2b, 128, NROW * 128);

  // --- head ---
  k_final<<<512, 256, 0, stream>>>(ws + PGB, ws + TGB, ws + GBUFO, mlpW, mlpb, outp);
}